// Round 7
// baseline (337.320 us; speedup 1.0000x reference)
//
#include <hip/hip_runtime.h>

// Local cost-volume correlation, fp32, DPP window sharing, 3-dy fusion.
// out[b, dy*9+dx, h, w] = (1/256) sum_c in1[b,c,h,w] * in2[b,c,h+dy-4,w+dx-4]
//
// R10 design (from R4..R9 post-mortems: VALUBusy pinned 38-41% and ~11
// waves/CU across ILP-depth / block-shape / LDS-size changes -> the
// invariant is CACHE-LINE TRAFFIC: 9 dy-blocks per tile re-stream the same
// in1 tile => 1.8 GB of L1-miss lines at ~11 TB/s = the 160 us floor.
// Lever: fuse 3 dy per block -> in1 amp 9x->3x, traffic ~0.75 GB):
//  - 2 px/lane (float2 loads), acc[3][2][9] = 54 regs; peak live ~100 VGPR,
//    safely under the 128 cliff (R5/R6 lesson)
//  - wave = 1 full row (64 lanes x 2 px = 128 cols): DPP window needs
//    +-2 lanes via CHAINED wave_shr:1 / wave_shl:1 (8 DPP per in2 row);
//    wave-boundary wrap == image edge -> zeroed at store (proven pattern)
//  - 8 waves = 4 rows x 2 channel-halves (R8-proven split-K), chunked
//    LDS reduce 3 rounds x 18 floats via red[256][19] (stride 19 coprime
//    32 -> 2 lanes/bank, conflict-free; R9-proven pattern)
//  - grid 576 = 8b x 24 bands(4 rows) x 3 dy-groups; XCD swizzle keeps a
//    tile's 3 dy-blocks on one XCD (L2 sharing of in2 rows)

#define CH 256
#define HALFC 128
#define HH 96
#define WW 128
#define CS (HH * WW)

__device__ __forceinline__ float wshr1(float x) {  // lane i <- lane i-1
  union { float f; int i; } u, o;
  u.f = x;
  o.i = __builtin_amdgcn_update_dpp(0, u.i, 0x138, 0xF, 0xF, true);
  return o.f;
}
__device__ __forceinline__ float wshl1(float x) {  // lane i <- lane i+1
  union { float f; int i; } u, o;
  u.f = x;
  o.i = __builtin_amdgcn_update_dpp(0, u.i, 0x130, 0xF, 0xF, true);
  return o.f;
}

// one in2 row: build w[0..9] = in2[px-4 .. px+5] via chained +-1 lane DPP,
// then 18 FMA into this row's 2x9 accumulators. All indexing static.
__device__ __forceinline__ void row_fma(float (&ak)[2][9], const float2 a,
                                        const float2 m) {
  float w[10];
  w[2] = wshr1(m.x);  w[3] = wshr1(m.y);   // px-2, px-1
  w[0] = wshr1(w[2]); w[1] = wshr1(w[3]);  // px-4, px-3
  w[4] = m.x;         w[5] = m.y;          // px,   px+1
  w[6] = wshl1(m.x);  w[7] = wshl1(m.y);   // px+2, px+3
  w[8] = wshl1(w[6]); w[9] = wshl1(w[7]);  // px+4, px+5
#pragma unroll
  for (int d = 0; d < 9; ++d) {
    ak[0][d] = fmaf(a.x, w[d],     ak[0][d]);
    ak[1][d] = fmaf(a.y, w[d + 1], ak[1][d]);
  }
}

__global__ __launch_bounds__(512, 4) void corr3dy(
    const float* __restrict__ in1, const float* __restrict__ in2,
    float* __restrict__ out)
{
  // ---- block decode, XCD-swizzled: tile's 3 dyg-blocks share blockIdx%8 ----
  const int j    = blockIdx.x;          // grid = 576
  const int xcd  = j & 7;
  const int s    = j >> 3;              // 0..71
  const int dyg  = s % 3;               // dy group: {0,1,2}->dy 3k..3k+2
  const int tq   = s / 3;               // 0..23
  const int tile = tq * 8 + xcd;        // 0..191
  const int band = tile % 24;
  const int b    = tile / 24;
  const int D    = dyg * 3 - 4;         // dyo of k=0

  // ---- thread decode: 2 ch-halves x 4 row-waves x 64 lanes x 2 px ----
  const int tid  = threadIdx.x;
  const int half = tid >> 8;                // channel half
  const int t    = tid & 255;
  const int wr   = t >> 6;                  // row within band
  const int lane = t & 63;
  const int h    = band * 4 + wr;           // 0..95
  const int px   = lane << 1;               // 0..126

  bool rowok[3];
  int  r2c[3];
#pragma unroll
  for (int k = 0; k < 3; ++k) {
    const int r2 = h + D + k;
    rowok[k] = (unsigned)r2 < (unsigned)HH;
    r2c[k]   = r2 < 0 ? 0 : (r2 > HH - 1 ? HH - 1 : r2);
  }

  const size_t cbase = ((size_t)b * CH + half * HALFC) * HH;
  const float* __restrict__ p1  = in1 + (cbase + h)      * WW + px;
  const float* __restrict__ p20 = in2 + (cbase + r2c[0]) * WW + px;
  const float* __restrict__ p21 = in2 + (cbase + r2c[1]) * WW + px;
  const float* __restrict__ p22 = in2 + (cbase + r2c[2]) * WW + px;

  float acc[3][2][9];
#pragma unroll
  for (int k = 0; k < 3; ++k)
#pragma unroll
    for (int p = 0; p < 2; ++p)
#pragma unroll
      for (int d = 0; d < 9; ++d) acc[k][p][d] = 0.f;

  // ---- channel loop: 128 channels per half ----
#pragma unroll 2
  for (int c = 0; c < HALFC; ++c) {
    const float2 a  = *(const float2*)p1;   p1  += CS;
    const float2 m0 = *(const float2*)p20;  p20 += CS;
    const float2 m1 = *(const float2*)p21;  p21 += CS;
    const float2 m2 = *(const float2*)p22;  p22 += CS;
    row_fma(acc[0], a, m0);
    row_fma(acc[1], a, m1);
    row_fma(acc[2], a, m2);
  }

  // ---- chunked cross-half reduce: 3 rounds x 18 floats, 19.5 KB LDS ----
  // stride 19 coprime with 32 banks -> 2 lanes/bank, conflict-free
  __shared__ float red[256][19];
#pragma unroll
  for (int k = 0; k < 3; ++k) {
    if (half) {
#pragma unroll
      for (int p = 0; p < 2; ++p)
#pragma unroll
        for (int d = 0; d < 9; ++d) red[t][p * 9 + d] = acc[k][p][d];
    }
    __syncthreads();
    if (!half) {
#pragma unroll
      for (int p = 0; p < 2; ++p)
#pragma unroll
        for (int d = 0; d < 9; ++d) acc[k][p][d] += red[t][p * 9 + d];
    }
    __syncthreads();   // WAR guard before next round
  }

  if (!half) {
    // ---- epilogue: zero OOB (row+col), scale, float2 store, 27 planes ----
    const float sc = 1.0f / (float)CH;
#pragma unroll
    for (int k = 0; k < 3; ++k) {
      const int dy = dyg * 3 + k;
      float* po = out + (((size_t)b * 81 + dy * 9) * HH + h) * WW + px;
#pragma unroll
      for (int d = 0; d < 9; ++d) {
        float2 v;
        const int c0 = px + d - 4;       // in2 col for p=0
        const int c1 = px + 1 + d - 4;   // in2 col for p=1
        v.x = (rowok[k] && (unsigned)c0 < (unsigned)WW) ? acc[k][0][d] * sc : 0.f;
        v.y = (rowok[k] && (unsigned)c1 < (unsigned)WW) ? acc[k][1][d] * sc : 0.f;
        *(float2*)po = v;
        po += (size_t)CS;  // next dx plane
      }
    }
  }
}

extern "C" void kernel_launch(void* const* d_in, const int* in_sizes, int n_in,
                              void* d_out, int out_size, void* d_ws, size_t ws_size,
                              hipStream_t stream) {
  const float* in1 = (const float*)d_in[0];
  const float* in2 = (const float*)d_in[1];
  float* out = (float*)d_out;
  hipLaunchKernelGGL(corr3dy, dim3(576), dim3(512), 0, stream, in1, in2, out);
}